// Round 1
// baseline (2679.467 us; speedup 1.0000x reference)
//
#include <hip/hip_runtime.h>
#include <math.h>

#define NPIX 32
#define BATCH 128
#define NCH 3
#define NFEAT 15552
#define NHALF 7776      // NFEAT/2
#define RANKR 16
#define MFFT 16384      // half of FFT_LEN=32768
#define MHALF 8192
#define NT 1024
#define PI_F 3.14159265358979323846f

// ---------------- complex helpers ----------------
__device__ __forceinline__ float2 cadd(float2 a, float2 b){ return make_float2(a.x+b.x, a.y+b.y); }
__device__ __forceinline__ float2 csub(float2 a, float2 b){ return make_float2(a.x-b.x, a.y-b.y); }
__device__ __forceinline__ float2 cmul(float2 a, float2 b){ return make_float2(a.x*b.x - a.y*b.y, a.x*b.y + a.y*b.x); }
__device__ __forceinline__ float2 cmulc(float2 a, float2 b){ /* a*conj(b) */ return make_float2(a.x*b.x + a.y*b.y, a.y*b.x - a.x*b.y); }

// ---------------- 32-pt FFT in registers ----------------
// forward twiddles W32^k = e^{-i pi k/16} = (cos, -sin)
__device__ __constant__ float TW32C[16] = {
  1.f, 0.98078528f, 0.92387953f, 0.83146961f,
  0.70710678f, 0.55557023f, 0.38268343f, 0.19509032f,
  0.f, -0.19509032f, -0.38268343f, -0.55557023f,
  -0.70710678f, -0.83146961f, -0.92387953f, -0.98078528f };
__device__ __constant__ float TW32S[16] = {
  0.f, -0.19509032f, -0.38268343f, -0.55557023f,
  -0.70710678f, -0.83146961f, -0.92387953f, -0.98078528f,
  -1.f, -0.98078528f, -0.92387953f, -0.83146961f,
  -0.70710678f, -0.55557023f, -0.38268343f, -0.19509032f };

// DIF: natural in -> bit-reversed out, forward sign
__device__ __forceinline__ void fft32_fwd(float2* c){
  #pragma unroll
  for (int s = 4; s >= 0; --s){
    const int h = 1 << s;
    #pragma unroll
    for (int k = 0; k < 32; k += 2*h){
      #pragma unroll
      for (int j = 0; j < h; ++j){
        int i0 = k + j, i1 = i0 + h;
        float2 u = c[i0], v = c[i1];
        c[i0] = cadd(u, v);
        int e = j << (4 - s);
        float2 wt = make_float2(TW32C[e], TW32S[e]);
        c[i1] = cmul(csub(u, v), wt);
      }
    }
  }
}
// DIT: bit-reversed in -> natural out, inverse sign (unscaled)
__device__ __forceinline__ void fft32_inv(float2* c){
  #pragma unroll
  for (int s = 0; s <= 4; ++s){
    const int h = 1 << s;
    #pragma unroll
    for (int k = 0; k < 32; k += 2*h){
      #pragma unroll
      for (int j = 0; j < h; ++j){
        int i0 = k + j, i1 = i0 + h;
        int e = j << (4 - s);
        float2 wt = make_float2(TW32C[e], -TW32S[e]);
        float2 u = c[i0];
        float2 t = cmul(c[i1], wt);
        c[i0] = cadd(u, t);
        c[i1] = csub(u, t);
      }
    }
  }
}

// 2D 32x32 FFT on LDS tile (rows padded to 33 to avoid bank conflicts).
// Uses threads 0..31 of the block; call with all threads (has barriers).
template<bool INV>
__device__ __forceinline__ void fft2_lds(float2 (*A)[33], int tid, float scale){
  if (tid < 32){
    float2 c[32];
    #pragma unroll
    for (int e = 0; e < 32; ++e) c[e] = A[tid][e];
    if (INV) fft32_inv(c); else fft32_fwd(c);
    #pragma unroll
    for (int e = 0; e < 32; ++e) A[tid][e] = c[e];
  }
  __syncthreads();
  if (tid < 32){
    float2 c[32];
    #pragma unroll
    for (int e = 0; e < 32; ++e) c[e] = A[e][tid];
    if (INV) fft32_inv(c); else fft32_fwd(c);
    #pragma unroll
    for (int e = 0; e < 32; ++e) A[e][tid] = make_float2(c[e].x*scale, c[e].y*scale);
  }
  __syncthreads();
}

// ---------------- big 16384-pt complex FFT in LDS ----------------
// tw[j] = e^{-2 pi i j / 16384}, j < 8192
__global__ void k_twiddle(float2* __restrict__ tw){
  int j = blockIdx.x*256 + threadIdx.x;
  if (j < MHALF){
    double a = -2.0 * 3.14159265358979323846 * (double)j / (double)MFFT;
    tw[j] = make_float2((float)cos(a), (float)sin(a));
  }
}

__device__ __forceinline__ int rev14(int f){ return (int)(__brev((unsigned)f) >> 18); }

// DIF forward: natural in -> bitrev out. 10 LDS stages + 4 register stages.
__device__ __forceinline__ void bigfft_fwd(float2* z, const float2* __restrict__ tw, int tid){
  #pragma unroll 1
  for (int s = 13; s >= 4; --s){
    const int h = 1 << s;
    for (int w = tid; w < MHALF; w += NT){
      const int j = w & (h - 1);
      const int i0 = ((w >> s) << (s + 1)) + j;
      const int i1 = i0 + h;
      float2 u = z[i0], v = z[i1];
      z[i0] = cadd(u, v);
      float2 wt = tw[j << (13 - s)];
      z[i1] = cmul(csub(u, v), wt);
    }
    __syncthreads();
  }
  {
    const int base = tid << 4;
    float2 c[16];
    #pragma unroll
    for (int r = 0; r < 16; ++r) c[r] = z[base + r];
    #pragma unroll
    for (int s = 3; s >= 0; --s){
      const int h = 1 << s;
      #pragma unroll
      for (int k = 0; k < 16; k += 2*h){
        #pragma unroll
        for (int j = 0; j < h; ++j){
          const int i0 = k + j, i1 = i0 + h;
          float2 u = c[i0], v = c[i1];
          c[i0] = cadd(u, v);
          float2 wt = tw[j << (13 - s)];
          c[i1] = cmul(csub(u, v), wt);
        }
      }
    }
    #pragma unroll
    for (int r = 0; r < 16; ++r) z[base + r] = c[r];
  }
  __syncthreads();
}

// DIT inverse: bitrev in -> natural out (unscaled). 4 register stages + 10 LDS stages.
__device__ __forceinline__ void bigfft_inv(float2* z, const float2* __restrict__ tw, int tid){
  {
    const int base = tid << 4;
    float2 c[16];
    #pragma unroll
    for (int r = 0; r < 16; ++r) c[r] = z[base + r];
    #pragma unroll
    for (int s = 0; s <= 3; ++s){
      const int h = 1 << s;
      #pragma unroll
      for (int k = 0; k < 16; k += 2*h){
        #pragma unroll
        for (int j = 0; j < h; ++j){
          const int i0 = k + j, i1 = i0 + h;
          float2 wt = tw[j << (13 - s)]; wt.y = -wt.y;
          float2 u = c[i0];
          float2 t = cmul(c[i1], wt);
          c[i0] = cadd(u, t);
          c[i1] = csub(u, t);
        }
      }
    }
    #pragma unroll
    for (int r = 0; r < 16; ++r) z[base + r] = c[r];
  }
  __syncthreads();
  #pragma unroll 1
  for (int s = 4; s <= 13; ++s){
    const int h = 1 << s;
    for (int w = tid; w < MHALF; w += NT){
      const int j = w & (h - 1);
      const int i0 = ((w >> s) << (s + 1)) + j;
      const int i1 = i0 + h;
      float2 wt = tw[j << (13 - s)]; wt.y = -wt.y;
      float2 u = z[i0];
      float2 t = cmul(z[i1], wt);
      z[i0] = cadd(u, t);
      z[i1] = csub(u, t);
    }
    __syncthreads();
  }
}

// After bigfft_fwd of packed z (z[k]=x[2k]+i x[2k+1]): turn Z into true rfft
// spectrum S. Layout: S[f] at slot rev14(f) for f<M, S[M] at slot MFFT.
__device__ __forceinline__ void rfft_unpack(float2* z, int tid){
  for (int f = tid; f <= MHALF; f += NT){
    if (f == 0){
      float2 Z0 = z[0];
      z[0]    = make_float2(Z0.x + Z0.y, 0.f);
      z[MFFT] = make_float2(Z0.x - Z0.y, 0.f);
    } else if (f == MHALF){
      int p = rev14(f);
      float2 Zf = z[p];
      z[p] = make_float2(Zf.x, -Zf.y);
    } else {
      int pf = rev14(f), pp = rev14(MFFT - f);
      float2 Zf = z[pf], Zp = z[pp];
      float2 E = make_float2(0.5f*(Zf.x + Zp.x), 0.5f*(Zf.y - Zp.y));
      float2 Q = make_float2(0.5f*(Zf.x - Zp.x), 0.5f*(Zf.y + Zp.y));
      float2 O = make_float2(Q.y, -Q.x);             // -i*Q
      float sn, cs; __sincosf((float)f * (PI_F / (float)MFFT), &sn, &cs);
      float2 T = cmul(make_float2(cs, -sn), O);      // W_N^f * O
      z[pf] = make_float2(E.x + T.x,  E.y + T.y);    // S[f]   = E + T
      z[pp] = make_float2(E.x - T.x, -E.y + T.y);    // S[M-f] = conj(E) - conj(T)
    }
  }
  __syncthreads();
}

// Inverse of rfft_unpack: spectrum S (same layout) -> packed Z ready for bigfft_inv.
__device__ __forceinline__ void rfft_pack(float2* z, int tid){
  for (int f = tid; f <= MHALF; f += NT){
    if (f == 0){
      float2 S0 = z[0], SM = z[MFFT];
      float2 E = make_float2(0.5f*(S0.x + SM.x), 0.5f*(S0.y - SM.y));
      float2 O = make_float2(0.5f*(S0.x - SM.x), 0.5f*(S0.y + SM.y));
      z[0] = make_float2(E.x - O.y, E.y + O.x);      // E + iO
    } else if (f == MHALF){
      int p = rev14(f);
      float2 S = z[p];
      z[p] = make_float2(S.x, -S.y);
    } else {
      int pf = rev14(f), pp = rev14(MFFT - f);
      float2 Sf = z[pf], Sp = z[pp];
      float2 E = make_float2(0.5f*(Sf.x + Sp.x), 0.5f*(Sf.y - Sp.y));
      float2 D = make_float2(0.5f*(Sf.x - Sp.x), 0.5f*(Sf.y + Sp.y));
      float sn, cs; __sincosf((float)f * (PI_F / (float)MFFT), &sn, &cs);
      float2 O = cmul(make_float2(cs, sn), D);       // W_N^{-f} * D
      z[pf] = make_float2(E.x - O.y,  E.y + O.x);    // Z[f]   = E + iO
      z[pp] = make_float2(E.x + O.y, -E.y + O.x);    // Z[M-f] = conj(E) + i conj(O)
    }
  }
  __syncthreads();
}

// ---------------- filters (Morlet bank), computed on device ----------------
__global__ void k_filters(float2* __restrict__ filt){
  int f = blockIdx.x;         // 0..15 psi, 16 phi
  int tid = threadIdx.x;      // 64 threads
  __shared__ float2 A[32][33];
  __shared__ float2 rg[64];
  __shared__ float  re_[64];
  bool isphi = (f == 16);
  float sigma, xi = 0.f, cth = 0.f, sth = 0.f;
  if (!isphi){
    int jj = f >> 3, l = f & 7;
    sigma = 0.8f * (float)(1 << jj);
    xi = 2.35619449019234f / (float)(1 << jj);        // 3*pi/4 / 2^j
    float th = (float)l * 0.39269908169872414f;       // l*pi/8
    cth = cosf(th); sth = sinf(th);
  } else sigma = 3.2f;
  float inv2s2 = 1.f / (2.f * sigma * sigma);
  float norm = 1.f / (2.f * PI_F * sigma * sigma);
  float2 lg = make_float2(0.f, 0.f);
  float le = 0.f;
  for (int p = tid; p < 1024; p += 64){
    int iy = p >> 5, ix = p & 31;
    float gy = (iy > 16) ? (float)(iy - 32) : (float)iy;
    float gx = (ix > 16) ? (float)(ix - 32) : (float)ix;
    float r2 = gx*gx + gy*gy;
    float env = expf(-r2 * inv2s2);
    if (isphi){
      A[iy][ix] = make_float2(env * norm, 0.f);
    } else {
      float xr = gx*cth + gy*sth;
      float sn, cs; __sincosf(xi * xr, &sn, &cs);
      float2 gab = make_float2(env*cs, env*sn);
      A[iy][ix] = gab;
      lg = cadd(lg, gab);
      le += env;
    }
  }
  if (!isphi){
    rg[tid] = lg; re_[tid] = le;
    __syncthreads();
    for (int s = 32; s > 0; s >>= 1){
      if (tid < s){ rg[tid] = cadd(rg[tid], rg[tid+s]); re_[tid] += re_[tid+s]; }
      __syncthreads();
    }
    float2 K = make_float2(rg[0].x / re_[0], rg[0].y / re_[0]);
    for (int p = tid; p < 1024; p += 64){
      int iy = p >> 5, ix = p & 31;
      float gy = (iy > 16) ? (float)(iy - 32) : (float)iy;
      float gx = (ix > 16) ? (float)(ix - 32) : (float)ix;
      float r2 = gx*gx + gy*gy;
      float env = expf(-r2 * inv2s2);
      float2 v = A[iy][ix];
      A[iy][ix] = make_float2((v.x - K.x*env) * norm, (v.y - K.y*env) * norm);
    }
  }
  __syncthreads();
  fft2_lds<false>(A, tid, 1.f);
  for (int p = tid; p < 1024; p += 64)
    filt[(size_t)f*1024 + p] = A[p >> 5][p & 31];
}

// ---------------- scattering ----------------
__global__ void k_scat1(const float* __restrict__ x, const float2* __restrict__ filt,
                        float2* __restrict__ xh, float* __restrict__ feat){
  int bc = blockIdx.x, tid = threadIdx.x;
  int b = bc / 3, ch = bc % 3;
  __shared__ float2 A[32][33];
  for (int p = tid; p < 1024; p += 64)
    A[p>>5][p&31] = make_float2(x[(size_t)bc*1024 + p], 0.f);
  __syncthreads();
  fft2_lds<false>(A, tid, 1.f);
  const float2* phi = filt + 16*1024;
  for (int p = tid; p < 1024; p += 64){
    float2 v = A[p>>5][p&31];
    xh[(size_t)bc*1024 + p] = v;
    A[p>>5][p&31] = cmul(v, phi[p]);
  }
  __syncthreads();
  fft2_lds<true>(A, tid, 1.f/1024.f);
  int py = tid >> 3, px = tid & 7;
  feat[(size_t)b*NFEAT + ch*5184 + tid] = A[4*py][4*px].x;
}

__global__ void k_scat2(const float2* __restrict__ xh, const float2* __restrict__ filt,
                        float2* __restrict__ u1h, float* __restrict__ feat){
  int id = blockIdx.x, tid = threadIdx.x;
  int bc = id >> 4, l1 = id & 15;
  int b = bc / 3, ch = bc % 3;
  __shared__ float2 A[32][33];
  const float2* psi = filt + (size_t)l1*1024;
  for (int p = tid; p < 1024; p += 64)
    A[p>>5][p&31] = cmul(xh[(size_t)bc*1024 + p], psi[p]);
  __syncthreads();
  fft2_lds<true>(A, tid, 1.f/1024.f);
  for (int p = tid; p < 1024; p += 64){
    float2 v = A[p>>5][p&31];
    A[p>>5][p&31] = make_float2(sqrtf(v.x*v.x + v.y*v.y), 0.f);
  }
  __syncthreads();
  fft2_lds<false>(A, tid, 1.f);
  const float2* phi = filt + 16*1024;
  for (int p = tid; p < 1024; p += 64){
    float2 v = A[p>>5][p&31];
    if (l1 < 8) u1h[((size_t)bc*8 + l1)*1024 + p] = v;
    A[p>>5][p&31] = cmul(v, phi[p]);
  }
  __syncthreads();
  fft2_lds<true>(A, tid, 1.f/1024.f);
  int py = tid >> 3, px = tid & 7;
  feat[(size_t)b*NFEAT + ch*5184 + (1 + l1)*64 + tid] = A[4*py][4*px].x;
}

__global__ void k_scat3(const float2* __restrict__ u1h, const float2* __restrict__ filt,
                        float* __restrict__ feat){
  int id = blockIdx.x, tid = threadIdx.x;
  int l2 = id & 7; int rest = id >> 3;
  int l1 = rest & 7; int bc = rest >> 3;
  int b = bc / 3, ch = bc % 3;
  __shared__ float2 A[32][33];
  const float2* psi = filt + (size_t)(8 + l2)*1024;
  for (int p = tid; p < 1024; p += 64)
    A[p>>5][p&31] = cmul(u1h[(size_t)rest*1024 + p], psi[p]);
  __syncthreads();
  fft2_lds<true>(A, tid, 1.f/1024.f);
  for (int p = tid; p < 1024; p += 64){
    float2 v = A[p>>5][p&31];
    A[p>>5][p&31] = make_float2(sqrtf(v.x*v.x + v.y*v.y), 0.f);
  }
  __syncthreads();
  fft2_lds<false>(A, tid, 1.f);
  const float2* phi = filt + 16*1024;
  for (int p = tid; p < 1024; p += 64)
    A[p>>5][p&31] = cmul(A[p>>5][p&31], phi[p]);
  __syncthreads();
  fft2_lds<true>(A, tid, 1.f/1024.f);
  int py = tid >> 3, px = tid & 7;
  feat[(size_t)b*NFEAT + ch*5184 + (17 + l1*8 + l2)*64 + tid] = A[4*py][4*px].x;
}

// ---------------- batchnorm (train mode) + relu, in place ----------------
__global__ void k_bn(float* __restrict__ feat, const float* __restrict__ gamma,
                     const float* __restrict__ beta){
  int k = blockIdx.x*256 + threadIdx.x;
  if (k >= NFEAT) return;
  float s = 0.f;
  for (int b = 0; b < BATCH; ++b) s += feat[(size_t)b*NFEAT + k];
  float mu = s * (1.f/BATCH);
  float v = 0.f;
  for (int b = 0; b < BATCH; ++b){ float d = feat[(size_t)b*NFEAT + k] - mu; v += d*d; }
  v *= (1.f/BATCH);
  float sc = rsqrtf(v + 1e-5f) * gamma[k];
  float bt = beta[k];
  for (int b = 0; b < BATCH; ++b){
    float val = (feat[(size_t)b*NFEAT + k] - mu) * sc + bt;
    feat[(size_t)b*NFEAT + k] = fmaxf(val, 0.f);
  }
}

// ---------------- cumprod P of subdiagonal ----------------
__global__ __launch_bounds__(1024) void k_scan(const float* __restrict__ subd, float* __restrict__ P){
  __shared__ float ss[2][1024];
  int t = threadIdx.x;
  float loc[16];
  float prod = 1.f;
  #pragma unroll
  for (int r = 0; r < 16; ++r){
    int idx = t*16 + r;
    float v = (idx < NFEAT-1) ? subd[idx] : 1.f;
    prod *= v;
    loc[r] = prod;
  }
  int cur = 0;
  ss[0][t] = prod;
  __syncthreads();
  for (int offd = 1; offd < 1024; offd <<= 1){
    float v = ss[cur][t];
    if (t >= offd) v *= ss[cur][t - offd];
    ss[cur^1][t] = v;
    cur ^= 1;
    __syncthreads();
  }
  float excl = (t == 0) ? 1.f : ss[cur][t-1];
  #pragma unroll
  for (int r = 0; r < 16; ++r){
    int k = t*16 + r;
    if (k < NFEAT) P[k] = (r == 0) ? excl : excl * loc[r-1];
  }
}

// ---------------- rfft of generator rows (G/P and H/P) ----------------
__global__ __launch_bounds__(1024) void k_rfft_gh(const float* __restrict__ Gl, const float* __restrict__ Hl,
                                                  const float* __restrict__ P, const float2* __restrict__ tw,
                                                  float2* __restrict__ Gf, float2* __restrict__ Hf){
  int j = blockIdx.x, tid = threadIdx.x;
  const float* row = (j < 16) ? (Hl + (size_t)j*NFEAT) : (Gl + (size_t)(j-16)*NFEAT);
  float2* outp = (j < 16) ? (Hf + (size_t)j*(MFFT+1)) : (Gf + (size_t)(j-16)*(MFFT+1));
  __shared__ float2 z[MFFT + 16];
  for (int k = tid; k < MFFT; k += NT){
    if (k < NHALF) z[k] = make_float2(row[2*k]/P[2*k], row[2*k+1]/P[2*k+1]);
    else z[k] = make_float2(0.f, 0.f);
  }
  __syncthreads();
  bigfft_fwd(z, tw, tid);
  rfft_unpack(z, tid);
  for (int p = tid; p <= MFFT; p += NT) outp[p] = z[p];
}

// ---------------- rfft of a = src * P ----------------
__global__ __launch_bounds__(1024) void k_rfft_a(const float* __restrict__ src, const float* __restrict__ P,
                                                 const float2* __restrict__ tw, float2* __restrict__ Af){
  int b = blockIdx.x, tid = threadIdx.x;
  __shared__ float2 z[MFFT + 16];
  for (int k = tid; k < MFFT; k += NT){
    if (k < NHALF){
      size_t i = (size_t)b*NFEAT + 2*k;
      z[k] = make_float2(src[i]*P[2*k], src[i+1]*P[2*k+1]);
    } else z[k] = make_float2(0.f, 0.f);
  }
  __syncthreads();
  bigfft_fwd(z, tw, tid);
  rfft_unpack(z, tid);
  for (int p = tid; p <= MFFT; p += NT) Af[(size_t)b*(MFFT+1) + p] = z[p];
}

// ---------------- main LDR loop: per (b, half) accumulate Y spectrum ----------------
__global__ __launch_bounds__(1024) void k_main(const float2* __restrict__ Af, const float2* __restrict__ Hf,
                                               const float2* __restrict__ Gf, const float2* __restrict__ tw,
                                               float2* __restrict__ Yp){
  int b = blockIdx.x >> 1, half = blockIdx.x & 1;
  int tid = threadIdx.x;
  __shared__ float2 z[MFFT + 16];
  float2 acc[16];
  #pragma unroll
  for (int r = 0; r < 16; ++r) acc[r] = make_float2(0.f, 0.f);
  float2 accM = make_float2(0.f, 0.f);
  const float2* Ab = Af + (size_t)b*(MFFT+1);
  for (int ii = 0; ii < 8; ++ii){
    int i = half*8 + ii;
    const float2* Hi = Hf + (size_t)i*(MFFT+1);
    const float2* Gi = Gf + (size_t)i*(MFFT+1);
    for (int p = tid; p <= MFFT; p += NT) z[p] = cmulc(Ab[p], Hi[p]);
    __syncthreads();
    rfft_pack(z, tid);
    bigfft_inv(z, tw, tid);       // gives M * c  (scale deferred)
    for (int k = NHALF + tid; k < MFFT; k += NT) z[k] = make_float2(0.f, 0.f);
    __syncthreads();
    bigfft_fwd(z, tw, tid);
    rfft_unpack(z, tid);          // M * Cf
    #pragma unroll
    for (int r = 0; r < 16; ++r){
      int p = r*NT + tid;
      acc[r] = cadd(acc[r], cmul(z[p], Gi[p]));
    }
    if (tid == 0) accM = cadd(accM, cmul(z[MFFT], Gi[MFFT]));
    __syncthreads();
  }
  float2* Yb = Yp + ((size_t)half*BATCH + b)*(MFFT+1);
  #pragma unroll
  for (int r = 0; r < 16; ++r) Yb[r*NT + tid] = acc[r];
  if (tid == 0) Yb[MFFT] = accM;
}

// ---------------- finish layer: inverse, scale, *P, relu ----------------
__global__ __launch_bounds__(1024) void k_fin(const float2* __restrict__ Yp, const float* __restrict__ P,
                                              const float2* __restrict__ tw, float* __restrict__ dst, int relu){
  int b = blockIdx.x, tid = threadIdx.x;
  __shared__ float2 z[MFFT + 16];
  for (int p = tid; p <= MFFT; p += NT)
    z[p] = cadd(Yp[(size_t)b*(MFFT+1) + p], Yp[((size_t)BATCH + b)*(MFFT+1) + p]);
  __syncthreads();
  rfft_pack(z, tid);
  bigfft_inv(z, tw, tid);
  const float s = 1.f / ((float)MFFT * (float)MFFT);   // two deferred 1/M factors
  for (int k = tid; k < NHALF; k += NT){
    float2 v = z[k];
    float y0 = v.x * s * P[2*k];
    float y1 = v.y * s * P[2*k+1];
    if (relu){ y0 = fmaxf(y0, 0.f); y1 = fmaxf(y1, 0.f); }
    dst[(size_t)b*NFEAT + 2*k]     = y0;
    dst[(size_t)b*NFEAT + 2*k + 1] = y1;
  }
}

// ---------------- last layer collapsed to 10 x NFEAT matrix ----------------
__global__ void k_wlast(const float* __restrict__ G2, const float* __restrict__ H2,
                        const float* __restrict__ P, float* __restrict__ Wl){
  int k = blockIdx.x*256 + threadIdx.x;
  if (k >= NFEAT) return;
  float Pk = P[k];
  for (int t = 0; t < 10; ++t){
    float s = 0.f;
    int jmax = (t < k) ? t : k;
    for (int i = 0; i < RANKR; ++i){
      const float* g = G2 + (size_t)i*NFEAT;
      const float* h = H2 + (size_t)i*NFEAT;
      for (int j = 0; j <= jmax; ++j){
        s += (g[t-j] * h[k-j]) / (P[t-j] * P[k-j]);
      }
    }
    Wl[(size_t)t*NFEAT + k] = P[t] * Pk * s;
  }
}

__global__ void k_out(const float* __restrict__ f, const float* __restrict__ Wl,
                      float* __restrict__ out){
  int b = blockIdx.x, tid = threadIdx.x;  // 256 threads
  float acc[10];
  #pragma unroll
  for (int t = 0; t < 10; ++t) acc[t] = 0.f;
  for (int k = tid; k < NFEAT; k += 256){
    float fv = f[(size_t)b*NFEAT + k];
    #pragma unroll
    for (int t = 0; t < 10; ++t) acc[t] += fv * Wl[(size_t)t*NFEAT + k];
  }
  __shared__ float red[10][256];
  #pragma unroll
  for (int t = 0; t < 10; ++t) red[t][tid] = acc[t];
  __syncthreads();
  for (int s = 128; s > 0; s >>= 1){
    if (tid < s){
      #pragma unroll
      for (int t = 0; t < 10; ++t) red[t][tid] += red[t][tid + s];
    }
    __syncthreads();
  }
  if (tid < 10) out[(size_t)b*10 + tid] = red[tid][0];
}

// ---------------- launch ----------------
extern "C" void kernel_launch(void* const* d_in, const int* in_sizes, int n_in,
                              void* d_out, int out_size, void* d_ws, size_t ws_size,
                              hipStream_t stream){
  (void)in_sizes; (void)n_in; (void)out_size; (void)ws_size;
  const float* x     = (const float*)d_in[0];
  const float* gamma = (const float*)d_in[1];
  const float* beta  = (const float*)d_in[2];
  const float* Gs    = (const float*)d_in[3];
  const float* Hs    = (const float*)d_in[4];
  const float* subds = (const float*)d_in[5];
  float* out = (float*)d_out;

  char* base = (char*)d_ws;
  size_t off = 0;
  auto alloc = [&](size_t bytes) -> char* {
    char* p = base + off;
    off += (bytes + 255) & ~(size_t)255;
    return p;
  };
  float2* tw   = (float2*)alloc(MHALF * sizeof(float2));
  float2* filt = (float2*)alloc(17 * 1024 * sizeof(float2));
  float*  feat = (float*)alloc((size_t)BATCH * NFEAT * sizeof(float));
  float*  ybuf = (float*)alloc((size_t)BATCH * NFEAT * sizeof(float));
  float*  P    = (float*)alloc(NFEAT * sizeof(float));
  float*  Wl   = (float*)alloc(10 * NFEAT * sizeof(float));
  // overlapped region: scattering {xh, u1h} then LDR {Af, Ypart, Gf, Hf}
  char* R = alloc(54529280);
  float2* xh  = (float2*)R;
  float2* u1h = (float2*)(R + 3145728);
  float2* Af  = (float2*)R;
  float2* Yp  = (float2*)(R + 16778240);
  float2* Gf  = (float2*)(R + 16778240 + 33556480);
  float2* Hf  = (float2*)(R + 16778240 + 33556480 + 2097280);

  k_twiddle<<<32, 256, 0, stream>>>(tw);
  k_filters<<<17, 64, 0, stream>>>(filt);
  k_scat1<<<BATCH*NCH, 64, 0, stream>>>(x, filt, xh, feat);
  k_scat2<<<BATCH*NCH*16, 64, 0, stream>>>(xh, filt, u1h, feat);
  k_scat3<<<BATCH*NCH*64, 64, 0, stream>>>(u1h, filt, feat);
  k_bn<<<(NFEAT+255)/256, 256, 0, stream>>>(feat, gamma, beta);

  for (int l = 0; l < 2; ++l){
    const float* src = (l == 0) ? feat : ybuf;
    float* dst = (l == 0) ? ybuf : feat;
    k_scan<<<1, 1024, 0, stream>>>(subds + (size_t)l*(NFEAT-1), P);
    k_rfft_gh<<<32, 1024, 0, stream>>>(Gs + (size_t)l*RANKR*NFEAT, Hs + (size_t)l*RANKR*NFEAT, P, tw, Gf, Hf);
    k_rfft_a<<<BATCH, 1024, 0, stream>>>(src, P, tw, Af);
    k_main<<<BATCH*2, 1024, 0, stream>>>(Af, Hf, Gf, tw, Yp);
    k_fin<<<BATCH, 1024, 0, stream>>>(Yp, P, tw, dst, 1);
  }

  k_scan<<<1, 1024, 0, stream>>>(subds + (size_t)2*(NFEAT-1), P);
  k_wlast<<<(NFEAT+255)/256, 256, 0, stream>>>(Gs + (size_t)2*RANKR*NFEAT, Hs + (size_t)2*RANKR*NFEAT, P, Wl);
  k_out<<<BATCH, 256, 0, stream>>>(feat, Wl, out);
}

// Round 2
// 1770.897 us; speedup vs baseline: 1.5131x; 1.5131x over previous
//
#include <hip/hip_runtime.h>
#include <math.h>

#define NPIX 32
#define BATCH 128
#define NCH 3
#define NFEAT 15552
#define NHALF 7776      // NFEAT/2
#define RANKR 16
#define MFFT 16384      // half of FFT_LEN=32768
#define MHALF 8192
#define NT 1024
#define PI_F 3.14159265358979323846f

// ---------------- complex helpers ----------------
__device__ __forceinline__ float2 cadd(float2 a, float2 b){ return make_float2(a.x+b.x, a.y+b.y); }
__device__ __forceinline__ float2 csub(float2 a, float2 b){ return make_float2(a.x-b.x, a.y-b.y); }
__device__ __forceinline__ float2 cmul(float2 a, float2 b){ return make_float2(a.x*b.x - a.y*b.y, a.x*b.y + a.y*b.x); }
__device__ __forceinline__ float2 cmulc(float2 a, float2 b){ /* a*conj(b) */ return make_float2(a.x*b.x + a.y*b.y, a.y*b.x - a.x*b.y); }

// LDS bank swizzle: spreads bitrev (stride-256) and tail (stride-16) patterns
// across all 16 bank-pairs while keeping linear patterns conflict-free.
__device__ __forceinline__ int swzi(int p){ return p ^ (((p>>4) ^ (p>>8)) & 15); }

// ---------------- 32-pt FFT in registers ----------------
__device__ __constant__ float TW32C[16] = {
  1.f, 0.98078528f, 0.92387953f, 0.83146961f,
  0.70710678f, 0.55557023f, 0.38268343f, 0.19509032f,
  0.f, -0.19509032f, -0.38268343f, -0.55557023f,
  -0.70710678f, -0.83146961f, -0.92387953f, -0.98078528f };
__device__ __constant__ float TW32S[16] = {
  0.f, -0.19509032f, -0.38268343f, -0.55557023f,
  -0.70710678f, -0.83146961f, -0.92387953f, -0.98078528f,
  -1.f, -0.98078528f, -0.92387953f, -0.83146961f,
  -0.70710678f, -0.55557023f, -0.38268343f, -0.19509032f };

__device__ __forceinline__ void fft32_fwd(float2* c){
  #pragma unroll
  for (int s = 4; s >= 0; --s){
    const int h = 1 << s;
    #pragma unroll
    for (int k = 0; k < 32; k += 2*h){
      #pragma unroll
      for (int j = 0; j < h; ++j){
        int i0 = k + j, i1 = i0 + h;
        float2 u = c[i0], v = c[i1];
        c[i0] = cadd(u, v);
        int e = j << (4 - s);
        float2 wt = make_float2(TW32C[e], TW32S[e]);
        c[i1] = cmul(csub(u, v), wt);
      }
    }
  }
}
__device__ __forceinline__ void fft32_inv(float2* c){
  #pragma unroll
  for (int s = 0; s <= 4; ++s){
    const int h = 1 << s;
    #pragma unroll
    for (int k = 0; k < 32; k += 2*h){
      #pragma unroll
      for (int j = 0; j < h; ++j){
        int i0 = k + j, i1 = i0 + h;
        int e = j << (4 - s);
        float2 wt = make_float2(TW32C[e], -TW32S[e]);
        float2 u = c[i0];
        float2 t = cmul(c[i1], wt);
        c[i0] = cadd(u, t);
        c[i1] = csub(u, t);
      }
    }
  }
}

template<bool INV>
__device__ __forceinline__ void fft2_lds(float2 (*A)[33], int tid, float scale){
  if (tid < 32){
    float2 c[32];
    #pragma unroll
    for (int e = 0; e < 32; ++e) c[e] = A[tid][e];
    if (INV) fft32_inv(c); else fft32_fwd(c);
    #pragma unroll
    for (int e = 0; e < 32; ++e) A[tid][e] = c[e];
  }
  __syncthreads();
  if (tid < 32){
    float2 c[32];
    #pragma unroll
    for (int e = 0; e < 32; ++e) c[e] = A[e][tid];
    if (INV) fft32_inv(c); else fft32_fwd(c);
    #pragma unroll
    for (int e = 0; e < 32; ++e) A[e][tid] = make_float2(c[e].x*scale, c[e].y*scale);
  }
  __syncthreads();
}

// ---------------- big 16384-pt complex FFT in LDS ----------------
__global__ void k_twiddle(float2* __restrict__ tw){
  int j = blockIdx.x*256 + threadIdx.x;
  if (j < MHALF){
    double a = -2.0 * 3.14159265358979323846 * (double)j / (double)MFFT;
    tw[j] = make_float2((float)cos(a), (float)sin(a));
  }
}

__device__ __forceinline__ int rev14(int f){ return (int)(__brev((unsigned)f) >> 18); }

// DIF forward: natural in -> bitrev out. 5 fused radix-2^2 LDS passes + radix-16 register tail.
__device__ __forceinline__ void bigfft_fwd(float2* z, const float2* __restrict__ tw, int tid){
  #pragma unroll 1
  for (int s = 13; s >= 5; s -= 2){
    const int hq = 1 << (s-1);
    #pragma unroll 1
    for (int w = tid; w < MFFT/4; w += NT){
      const int j = w & (hq - 1);
      const int i0 = ((w >> (s-1)) << (s+1)) + j;
      const int p0 = swzi(i0), p1 = swzi(i0+hq), p2 = swzi(i0+2*hq), p3 = swzi(i0+3*hq);
      float2 a0 = z[p0], a1 = z[p1], a2 = z[p2], a3 = z[p3];
      const int e1 = j << (13 - s);
      const float2 wA = tw[e1];
      const float2 wB = tw[e1 + 4096];
      const float2 wC = tw[j << (14 - s)];
      float2 t0 = cadd(a0, a2);
      float2 t2 = cmul(csub(a0, a2), wA);
      float2 t1 = cadd(a1, a3);
      float2 t3 = cmul(csub(a1, a3), wB);
      z[p0] = cadd(t0, t1);
      z[p1] = cmul(csub(t0, t1), wC);
      z[p2] = cadd(t2, t3);
      z[p3] = cmul(csub(t2, t3), wC);
    }
    __syncthreads();
  }
  {
    const int base = tid << 4;
    float2 c[16];
    #pragma unroll
    for (int r = 0; r < 16; ++r) c[r] = z[swzi(base + r)];
    #pragma unroll
    for (int s = 3; s >= 0; --s){
      const int h = 1 << s;
      #pragma unroll
      for (int k = 0; k < 16; k += 2*h){
        #pragma unroll
        for (int j = 0; j < h; ++j){
          const int i0 = k + j, i1 = i0 + h;
          float2 u = c[i0], v = c[i1];
          c[i0] = cadd(u, v);
          float2 wt = tw[j << (13 - s)];
          c[i1] = cmul(csub(u, v), wt);
        }
      }
    }
    #pragma unroll
    for (int r = 0; r < 16; ++r) z[swzi(base + r)] = c[r];
  }
  __syncthreads();
}

// DIT inverse: bitrev in -> natural out (unscaled). Register tail + 5 fused passes.
// TRUNC: fold the zeroing of positions >= NHALF into the last pass.
template<bool TRUNC>
__device__ __forceinline__ void bigfft_inv(float2* z, const float2* __restrict__ tw, int tid){
  {
    const int base = tid << 4;
    float2 c[16];
    #pragma unroll
    for (int r = 0; r < 16; ++r) c[r] = z[swzi(base + r)];
    #pragma unroll
    for (int s = 0; s <= 3; ++s){
      const int h = 1 << s;
      #pragma unroll
      for (int k = 0; k < 16; k += 2*h){
        #pragma unroll
        for (int j = 0; j < h; ++j){
          const int i0 = k + j, i1 = i0 + h;
          float2 wt = tw[j << (13 - s)]; wt.y = -wt.y;
          float2 u = c[i0];
          float2 t = cmul(c[i1], wt);
          c[i0] = cadd(u, t);
          c[i1] = csub(u, t);
        }
      }
    }
    #pragma unroll
    for (int r = 0; r < 16; ++r) z[swzi(base + r)] = c[r];
  }
  __syncthreads();
  #pragma unroll 1
  for (int s = 4; s <= 12; s += 2){
    const int h = 1 << s;
    #pragma unroll 1
    for (int w = tid; w < MFFT/4; w += NT){
      const int j = w & (h - 1);
      const int i0 = ((w >> s) << (s + 2)) + j;
      const int p0 = swzi(i0), p1 = swzi(i0+h), p2 = swzi(i0+2*h), p3 = swzi(i0+3*h);
      float2 a0 = z[p0], a1 = z[p1], a2 = z[p2], a3 = z[p3];
      const int e1 = j << (13 - s);
      float2 wt = tw[e1]; wt.y = -wt.y;
      float2 m1 = cmul(a1, wt), m3 = cmul(a3, wt);
      float2 t0 = cadd(a0, m1), t1 = csub(a0, m1);
      float2 t2 = cadd(a2, m3), t3 = csub(a2, m3);
      const int e2 = j << (12 - s);
      float2 w0 = tw[e2]; w0.y = -w0.y;
      float2 w1 = tw[e2 + 4096]; w1.y = -w1.y;
      float2 u2 = cmul(t2, w0), u3 = cmul(t3, w1);
      if (TRUNC && s == 12){
        z[p0] = cadd(t0, u2);
        float2 v1 = cadd(t1, u3);
        z[p1] = (i0 + h >= NHALF) ? make_float2(0.f, 0.f) : v1;
        z[p2] = make_float2(0.f, 0.f);
        z[p3] = make_float2(0.f, 0.f);
      } else {
        z[p0] = cadd(t0, u2);
        z[p2] = csub(t0, u2);
        z[p1] = cadd(t1, u3);
        z[p3] = csub(t1, u3);
      }
    }
    __syncthreads();
  }
}

// Pack a natural-order real-FFT spectrum (provided by Sget(f), f in [0,MFFT])
// into the packed complex-Z slot layout ready for bigfft_inv.
template<typename F>
__device__ __forceinline__ void rfft_pack_f(float2* z, int tid, F Sget){
  for (int f = tid; f <= MHALF; f += NT){
    if (f == 0){
      float2 S0 = Sget(0), SM = Sget(MFFT);
      float2 E = make_float2(0.5f*(S0.x + SM.x), 0.5f*(S0.y - SM.y));
      float2 O = make_float2(0.5f*(S0.x - SM.x), 0.5f*(S0.y + SM.y));
      z[0] = make_float2(E.x - O.y, E.y + O.x);
    } else if (f == MHALF){
      float2 S = Sget(MHALF);
      z[swzi(1)] = make_float2(S.x, -S.y);
    } else {
      float2 Sf = Sget(f), Sp = Sget(MFFT - f);
      float2 E = make_float2(0.5f*(Sf.x + Sp.x), 0.5f*(Sf.y - Sp.y));
      float2 D = make_float2(0.5f*(Sf.x - Sp.x), 0.5f*(Sf.y + Sp.y));
      float sn, cs; __sincosf((float)f * (PI_F / (float)MFFT), &sn, &cs);
      float2 O = cmul(make_float2(cs, sn), D);
      int pf = rev14(f), pp = rev14(MFFT - f);
      z[swzi(pf)] = make_float2(E.x - O.y,  E.y + O.x);
      z[swzi(pp)] = make_float2(E.x + O.y, -E.y + O.x);
    }
  }
  __syncthreads();
}

// After bigfft_fwd of packed z: produce the true rfft spectrum in NATURAL order to out.
__device__ __forceinline__ void rfft_unpack_store(const float2* z, int tid, float2* __restrict__ out){
  for (int f = tid; f <= MHALF; f += NT){
    if (f == 0){
      float2 Z0 = z[0];
      out[0]    = make_float2(Z0.x + Z0.y, 0.f);
      out[MFFT] = make_float2(Z0.x - Z0.y, 0.f);
    } else if (f == MHALF){
      float2 Zf = z[swzi(1)];
      out[MHALF] = make_float2(Zf.x, -Zf.y);
    } else {
      int pf = rev14(f), pp = rev14(MFFT - f);
      float2 Zf = z[swzi(pf)], Zp = z[swzi(pp)];
      float2 E = make_float2(0.5f*(Zf.x + Zp.x), 0.5f*(Zf.y - Zp.y));
      float2 Q = make_float2(0.5f*(Zf.x - Zp.x), 0.5f*(Zf.y + Zp.y));
      float2 O = make_float2(Q.y, -Q.x);
      float sn, cs; __sincosf((float)f * (PI_F / (float)MFFT), &sn, &cs);
      float2 T = cmul(make_float2(cs, -sn), O);
      out[f]        = make_float2(E.x + T.x, E.y + T.y);
      out[MFFT - f] = make_float2(E.x - T.x, T.y - E.y);
    }
  }
}

// ---------------- filters (Morlet bank), computed on device ----------------
__global__ void k_filters(float2* __restrict__ filt){
  int f = blockIdx.x;
  int tid = threadIdx.x;
  __shared__ float2 A[32][33];
  __shared__ float2 rg[64];
  __shared__ float  re_[64];
  bool isphi = (f == 16);
  float sigma, xi = 0.f, cth = 0.f, sth = 0.f;
  if (!isphi){
    int jj = f >> 3, l = f & 7;
    sigma = 0.8f * (float)(1 << jj);
    xi = 2.35619449019234f / (float)(1 << jj);
    float th = (float)l * 0.39269908169872414f;
    cth = cosf(th); sth = sinf(th);
  } else sigma = 3.2f;
  float inv2s2 = 1.f / (2.f * sigma * sigma);
  float norm = 1.f / (2.f * PI_F * sigma * sigma);
  float2 lg = make_float2(0.f, 0.f);
  float le = 0.f;
  for (int p = tid; p < 1024; p += 64){
    int iy = p >> 5, ix = p & 31;
    float gy = (iy > 16) ? (float)(iy - 32) : (float)iy;
    float gx = (ix > 16) ? (float)(ix - 32) : (float)ix;
    float r2 = gx*gx + gy*gy;
    float env = expf(-r2 * inv2s2);
    if (isphi){
      A[iy][ix] = make_float2(env * norm, 0.f);
    } else {
      float xr = gx*cth + gy*sth;
      float sn, cs; __sincosf(xi * xr, &sn, &cs);
      float2 gab = make_float2(env*cs, env*sn);
      A[iy][ix] = gab;
      lg = cadd(lg, gab);
      le += env;
    }
  }
  if (!isphi){
    rg[tid] = lg; re_[tid] = le;
    __syncthreads();
    for (int s = 32; s > 0; s >>= 1){
      if (tid < s){ rg[tid] = cadd(rg[tid], rg[tid+s]); re_[tid] += re_[tid+s]; }
      __syncthreads();
    }
    float2 K = make_float2(rg[0].x / re_[0], rg[0].y / re_[0]);
    for (int p = tid; p < 1024; p += 64){
      int iy = p >> 5, ix = p & 31;
      float gy = (iy > 16) ? (float)(iy - 32) : (float)iy;
      float gx = (ix > 16) ? (float)(ix - 32) : (float)ix;
      float r2 = gx*gx + gy*gy;
      float env = expf(-r2 * inv2s2);
      float2 v = A[iy][ix];
      A[iy][ix] = make_float2((v.x - K.x*env) * norm, (v.y - K.y*env) * norm);
    }
  }
  __syncthreads();
  fft2_lds<false>(A, tid, 1.f);
  for (int p = tid; p < 1024; p += 64)
    filt[(size_t)f*1024 + p] = A[p >> 5][p & 31];
}

// ---------------- scattering ----------------
__global__ void k_scat1(const float* __restrict__ x, const float2* __restrict__ filt,
                        float2* __restrict__ xh, float* __restrict__ feat){
  int bc = blockIdx.x, tid = threadIdx.x;
  int b = bc / 3, ch = bc % 3;
  __shared__ float2 A[32][33];
  for (int p = tid; p < 1024; p += 64)
    A[p>>5][p&31] = make_float2(x[(size_t)bc*1024 + p], 0.f);
  __syncthreads();
  fft2_lds<false>(A, tid, 1.f);
  const float2* phi = filt + 16*1024;
  for (int p = tid; p < 1024; p += 64){
    float2 v = A[p>>5][p&31];
    xh[(size_t)bc*1024 + p] = v;
    A[p>>5][p&31] = cmul(v, phi[p]);
  }
  __syncthreads();
  fft2_lds<true>(A, tid, 1.f/1024.f);
  int py = tid >> 3, px = tid & 7;
  feat[(size_t)b*NFEAT + ch*5184 + tid] = A[4*py][4*px].x;
}

__global__ void k_scat2(const float2* __restrict__ xh, const float2* __restrict__ filt,
                        float2* __restrict__ u1h, float* __restrict__ feat){
  int id = blockIdx.x, tid = threadIdx.x;
  int bc = id >> 4, l1 = id & 15;
  int b = bc / 3, ch = bc % 3;
  __shared__ float2 A[32][33];
  const float2* psi = filt + (size_t)l1*1024;
  for (int p = tid; p < 1024; p += 64)
    A[p>>5][p&31] = cmul(xh[(size_t)bc*1024 + p], psi[p]);
  __syncthreads();
  fft2_lds<true>(A, tid, 1.f/1024.f);
  for (int p = tid; p < 1024; p += 64){
    float2 v = A[p>>5][p&31];
    A[p>>5][p&31] = make_float2(sqrtf(v.x*v.x + v.y*v.y), 0.f);
  }
  __syncthreads();
  fft2_lds<false>(A, tid, 1.f);
  const float2* phi = filt + 16*1024;
  for (int p = tid; p < 1024; p += 64){
    float2 v = A[p>>5][p&31];
    if (l1 < 8) u1h[((size_t)bc*8 + l1)*1024 + p] = v;
    A[p>>5][p&31] = cmul(v, phi[p]);
  }
  __syncthreads();
  fft2_lds<true>(A, tid, 1.f/1024.f);
  int py = tid >> 3, px = tid & 7;
  feat[(size_t)b*NFEAT + ch*5184 + (1 + l1)*64 + tid] = A[4*py][4*px].x;
}

__global__ void k_scat3(const float2* __restrict__ u1h, const float2* __restrict__ filt,
                        float* __restrict__ feat){
  int id = blockIdx.x, tid = threadIdx.x;
  int l2 = id & 7; int rest = id >> 3;
  int l1 = rest & 7; int bc = rest >> 3;
  int b = bc / 3, ch = bc % 3;
  __shared__ float2 A[32][33];
  const float2* psi = filt + (size_t)(8 + l2)*1024;
  for (int p = tid; p < 1024; p += 64)
    A[p>>5][p&31] = cmul(u1h[(size_t)rest*1024 + p], psi[p]);
  __syncthreads();
  fft2_lds<true>(A, tid, 1.f/1024.f);
  for (int p = tid; p < 1024; p += 64){
    float2 v = A[p>>5][p&31];
    A[p>>5][p&31] = make_float2(sqrtf(v.x*v.x + v.y*v.y), 0.f);
  }
  __syncthreads();
  fft2_lds<false>(A, tid, 1.f);
  const float2* phi = filt + 16*1024;
  for (int p = tid; p < 1024; p += 64)
    A[p>>5][p&31] = cmul(A[p>>5][p&31], phi[p]);
  __syncthreads();
  fft2_lds<true>(A, tid, 1.f/1024.f);
  int py = tid >> 3, px = tid & 7;
  feat[(size_t)b*NFEAT + ch*5184 + (17 + l1*8 + l2)*64 + tid] = A[4*py][4*px].x;
}

// ---------------- batchnorm (train mode) + relu, in place ----------------
__global__ void k_bn(float* __restrict__ feat, const float* __restrict__ gamma,
                     const float* __restrict__ beta){
  int k = blockIdx.x*256 + threadIdx.x;
  if (k >= NFEAT) return;
  float s = 0.f;
  for (int b = 0; b < BATCH; ++b) s += feat[(size_t)b*NFEAT + k];
  float mu = s * (1.f/BATCH);
  float v = 0.f;
  for (int b = 0; b < BATCH; ++b){ float d = feat[(size_t)b*NFEAT + k] - mu; v += d*d; }
  v *= (1.f/BATCH);
  float sc = rsqrtf(v + 1e-5f) * gamma[k];
  float bt = beta[k];
  for (int b = 0; b < BATCH; ++b){
    float val = (feat[(size_t)b*NFEAT + k] - mu) * sc + bt;
    feat[(size_t)b*NFEAT + k] = fmaxf(val, 0.f);
  }
}

// ---------------- cumprod P of subdiagonal ----------------
__global__ __launch_bounds__(1024) void k_scan(const float* __restrict__ subd, float* __restrict__ P){
  __shared__ float ss[2][1024];
  int t = threadIdx.x;
  float loc[16];
  float prod = 1.f;
  #pragma unroll
  for (int r = 0; r < 16; ++r){
    int idx = t*16 + r;
    float v = (idx < NFEAT-1) ? subd[idx] : 1.f;
    prod *= v;
    loc[r] = prod;
  }
  int cur = 0;
  ss[0][t] = prod;
  __syncthreads();
  for (int offd = 1; offd < 1024; offd <<= 1){
    float v = ss[cur][t];
    if (t >= offd) v *= ss[cur][t - offd];
    ss[cur^1][t] = v;
    cur ^= 1;
    __syncthreads();
  }
  float excl = (t == 0) ? 1.f : ss[cur][t-1];
  #pragma unroll
  for (int r = 0; r < 16; ++r){
    int k = t*16 + r;
    if (k < NFEAT) P[k] = (r == 0) ? excl : excl * loc[r-1];
  }
}

// ---------------- rfft of generator rows (G/P and H/P), natural-order out ----------------
__global__ __launch_bounds__(1024) void k_rfft_gh(const float* __restrict__ Gl, const float* __restrict__ Hl,
                                                  const float* __restrict__ P, const float2* __restrict__ tw,
                                                  float2* __restrict__ Gf, float2* __restrict__ Hf){
  int j = blockIdx.x, tid = threadIdx.x;
  const float* row = (j < 16) ? (Hl + (size_t)j*NFEAT) : (Gl + (size_t)(j-16)*NFEAT);
  float2* outp = (j < 16) ? (Hf + (size_t)j*(MFFT+1)) : (Gf + (size_t)(j-16)*(MFFT+1));
  __shared__ float2 z[MFFT + 16];
  for (int k = tid; k < MFFT; k += NT){
    float2 v = make_float2(0.f, 0.f);
    if (k < NHALF) v = make_float2(row[2*k]/P[2*k], row[2*k+1]/P[2*k+1]);
    z[swzi(k)] = v;
  }
  __syncthreads();
  bigfft_fwd(z, tw, tid);
  rfft_unpack_store(z, tid, outp);
}

// ---------------- rfft of a = src * P, natural-order out ----------------
__global__ __launch_bounds__(1024) void k_rfft_a(const float* __restrict__ src, const float* __restrict__ P,
                                                 const float2* __restrict__ tw, float2* __restrict__ Af){
  int b = blockIdx.x, tid = threadIdx.x;
  __shared__ float2 z[MFFT + 16];
  for (int k = tid; k < MFFT; k += NT){
    float2 v = make_float2(0.f, 0.f);
    if (k < NHALF){
      size_t i = (size_t)b*NFEAT + 2*k;
      v = make_float2(src[i]*P[2*k], src[i+1]*P[2*k+1]);
    }
    z[swzi(k)] = v;
  }
  __syncthreads();
  bigfft_fwd(z, tw, tid);
  rfft_unpack_store(z, tid, Af + (size_t)b*(MFFT+1));
}

// ---------------- main LDR loop: per (b, half) accumulate Y spectrum ----------------
__global__ __launch_bounds__(1024) void k_main(const float2* __restrict__ Af, const float2* __restrict__ Hf,
                                               const float2* __restrict__ Gf, const float2* __restrict__ tw,
                                               float2* __restrict__ Yp){
  int b = blockIdx.x >> 1, half = blockIdx.x & 1;
  int tid = threadIdx.x;
  __shared__ float2 z[MFFT + 16];
  float2 accA[8], accB[8];
  #pragma unroll
  for (int r = 0; r < 8; ++r){ accA[r] = make_float2(0.f,0.f); accB[r] = make_float2(0.f,0.f); }
  float2 accC = make_float2(0.f, 0.f);
  const float2* Ab = Af + (size_t)b*(MFFT+1);
  for (int ii = 0; ii < 8; ++ii){
    int i = half*8 + ii;
    const float2* Hi = Hf + (size_t)i*(MFFT+1);
    const float2* Gi = Gf + (size_t)i*(MFFT+1);
    // fused pointwise product (natural-order, coalesced) + pack into slots
    rfft_pack_f(z, tid, [&](int f){ return cmulc(Ab[f], Hi[f]); });
    bigfft_inv<true>(z, tw, tid);     // M * c, tail >= NHALF zeroed in last pass
    bigfft_fwd(z, tw, tid);           // M * Cf (slots)
    // fused unpack + multiply by Gf + accumulate (natural-order Gi reads, coalesced)
    #pragma unroll 1
    for (int k = 0; k < 8; ++k){
      int f = k*NT + tid;
      if (f == 0){
        float2 Z0 = z[0];
        accA[0] = cadd(accA[0], cmul(make_float2(Z0.x + Z0.y, 0.f), Gi[0]));
        accB[0] = cadd(accB[0], cmul(make_float2(Z0.x - Z0.y, 0.f), Gi[MFFT]));
      } else {
        int pf = rev14(f), pp = rev14(MFFT - f);
        float2 Zf = z[swzi(pf)], Zp = z[swzi(pp)];
        float2 E = make_float2(0.5f*(Zf.x + Zp.x), 0.5f*(Zf.y - Zp.y));
        float2 Q = make_float2(0.5f*(Zf.x - Zp.x), 0.5f*(Zf.y + Zp.y));
        float2 O = make_float2(Q.y, -Q.x);
        float sn, cs; __sincosf((float)f * (PI_F / (float)MFFT), &sn, &cs);
        float2 T = cmul(make_float2(cs, -sn), O);
        float2 Sf = make_float2(E.x + T.x, E.y + T.y);
        float2 Sm = make_float2(E.x - T.x, T.y - E.y);
        accA[k] = cadd(accA[k], cmul(Sf, Gi[f]));
        accB[k] = cadd(accB[k], cmul(Sm, Gi[MFFT - f]));
      }
    }
    if (tid == 0){
      float2 Zf = z[swzi(1)];
      accC = cadd(accC, cmul(make_float2(Zf.x, -Zf.y), Gi[MHALF]));
    }
    __syncthreads();
  }
  float2* Yb = Yp + ((size_t)half*BATCH + b)*(MFFT+1);
  #pragma unroll
  for (int k = 0; k < 8; ++k){
    int f = k*NT + tid;
    if (f == 0){
      Yb[0]    = accA[0];
      Yb[MFFT] = accB[0];
    } else {
      Yb[f]        = accA[k];
      Yb[MFFT - f] = accB[k];
    }
  }
  if (tid == 0) Yb[MHALF] = accC;
}

// ---------------- finish layer: inverse, scale, *P, relu ----------------
__global__ __launch_bounds__(1024) void k_fin(const float2* __restrict__ Yp, const float* __restrict__ P,
                                              const float2* __restrict__ tw, float* __restrict__ dst, int relu){
  int b = blockIdx.x, tid = threadIdx.x;
  __shared__ float2 z[MFFT + 16];
  const float2* Y0 = Yp + (size_t)b*(MFFT+1);
  const float2* Y1 = Yp + ((size_t)BATCH + b)*(MFFT+1);
  rfft_pack_f(z, tid, [&](int f){ return cadd(Y0[f], Y1[f]); });
  bigfft_inv<false>(z, tw, tid);
  const float s = 1.f / ((float)MFFT * (float)MFFT);   // two deferred 1/M factors
  for (int k = tid; k < NHALF; k += NT){
    float2 v = z[swzi(k)];
    float y0 = v.x * s * P[2*k];
    float y1 = v.y * s * P[2*k+1];
    if (relu){ y0 = fmaxf(y0, 0.f); y1 = fmaxf(y1, 0.f); }
    dst[(size_t)b*NFEAT + 2*k]     = y0;
    dst[(size_t)b*NFEAT + 2*k + 1] = y1;
  }
}

// ---------------- last layer collapsed to 10 x NFEAT matrix ----------------
__global__ void k_wlast(const float* __restrict__ G2, const float* __restrict__ H2,
                        const float* __restrict__ P, float* __restrict__ Wl){
  int k = blockIdx.x*256 + threadIdx.x;
  if (k >= NFEAT) return;
  float Pk = P[k];
  for (int t = 0; t < 10; ++t){
    float s = 0.f;
    int jmax = (t < k) ? t : k;
    for (int i = 0; i < RANKR; ++i){
      const float* g = G2 + (size_t)i*NFEAT;
      const float* h = H2 + (size_t)i*NFEAT;
      for (int j = 0; j <= jmax; ++j){
        s += (g[t-j] * h[k-j]) / (P[t-j] * P[k-j]);
      }
    }
    Wl[(size_t)t*NFEAT + k] = P[t] * Pk * s;
  }
}

__global__ void k_out(const float* __restrict__ f, const float* __restrict__ Wl,
                      float* __restrict__ out){
  int b = blockIdx.x, tid = threadIdx.x;  // 256 threads
  float acc[10];
  #pragma unroll
  for (int t = 0; t < 10; ++t) acc[t] = 0.f;
  for (int k = tid; k < NFEAT; k += 256){
    float fv = f[(size_t)b*NFEAT + k];
    #pragma unroll
    for (int t = 0; t < 10; ++t) acc[t] += fv * Wl[(size_t)t*NFEAT + k];
  }
  __shared__ float red[10][256];
  #pragma unroll
  for (int t = 0; t < 10; ++t) red[t][tid] = acc[t];
  __syncthreads();
  for (int s = 128; s > 0; s >>= 1){
    if (tid < s){
      #pragma unroll
      for (int t = 0; t < 10; ++t) red[t][tid] += red[t][tid + s];
    }
    __syncthreads();
  }
  if (tid < 10) out[(size_t)b*10 + tid] = red[tid][0];
}

// ---------------- launch ----------------
extern "C" void kernel_launch(void* const* d_in, const int* in_sizes, int n_in,
                              void* d_out, int out_size, void* d_ws, size_t ws_size,
                              hipStream_t stream){
  (void)in_sizes; (void)n_in; (void)out_size; (void)ws_size;
  const float* x     = (const float*)d_in[0];
  const float* gamma = (const float*)d_in[1];
  const float* beta  = (const float*)d_in[2];
  const float* Gs    = (const float*)d_in[3];
  const float* Hs    = (const float*)d_in[4];
  const float* subds = (const float*)d_in[5];
  float* out = (float*)d_out;

  char* base = (char*)d_ws;
  size_t off = 0;
  auto alloc = [&](size_t bytes) -> char* {
    char* p = base + off;
    off += (bytes + 255) & ~(size_t)255;
    return p;
  };
  float2* tw   = (float2*)alloc(MHALF * sizeof(float2));
  float2* filt = (float2*)alloc(17 * 1024 * sizeof(float2));
  float*  feat = (float*)alloc((size_t)BATCH * NFEAT * sizeof(float));
  float*  ybuf = (float*)alloc((size_t)BATCH * NFEAT * sizeof(float));
  float*  P    = (float*)alloc(NFEAT * sizeof(float));
  float*  Wl   = (float*)alloc(10 * NFEAT * sizeof(float));
  // overlapped region: scattering {xh, u1h} then LDR {Af, Ypart, Gf, Hf}
  char* R = alloc(54529280);
  float2* xh  = (float2*)R;
  float2* u1h = (float2*)(R + 3145728);
  float2* Af  = (float2*)R;
  float2* Yp  = (float2*)(R + 16778240);
  float2* Gf  = (float2*)(R + 16778240 + 33556480);
  float2* Hf  = (float2*)(R + 16778240 + 33556480 + 2097280);

  k_twiddle<<<32, 256, 0, stream>>>(tw);
  k_filters<<<17, 64, 0, stream>>>(filt);
  k_scat1<<<BATCH*NCH, 64, 0, stream>>>(x, filt, xh, feat);
  k_scat2<<<BATCH*NCH*16, 64, 0, stream>>>(xh, filt, u1h, feat);
  k_scat3<<<BATCH*NCH*64, 64, 0, stream>>>(u1h, filt, feat);
  k_bn<<<(NFEAT+255)/256, 256, 0, stream>>>(feat, gamma, beta);

  for (int l = 0; l < 2; ++l){
    const float* src = (l == 0) ? feat : ybuf;
    float* dst = (l == 0) ? ybuf : feat;
    k_scan<<<1, 1024, 0, stream>>>(subds + (size_t)l*(NFEAT-1), P);
    k_rfft_gh<<<32, 1024, 0, stream>>>(Gs + (size_t)l*RANKR*NFEAT, Hs + (size_t)l*RANKR*NFEAT, P, tw, Gf, Hf);
    k_rfft_a<<<BATCH, 1024, 0, stream>>>(src, P, tw, Af);
    k_main<<<BATCH*2, 1024, 0, stream>>>(Af, Hf, Gf, tw, Yp);
    k_fin<<<BATCH, 1024, 0, stream>>>(Yp, P, tw, dst, 1);
  }

  k_scan<<<1, 1024, 0, stream>>>(subds + (size_t)2*(NFEAT-1), P);
  k_wlast<<<(NFEAT+255)/256, 256, 0, stream>>>(Gs + (size_t)2*RANKR*NFEAT, Hs + (size_t)2*RANKR*NFEAT, P, Wl);
  k_out<<<BATCH, 256, 0, stream>>>(feat, Wl, out);
}